// Round 11
// baseline (159.171 us; speedup 1.0000x reference)
//
#include <hip/hip_runtime.h>

using u16    = unsigned short;
using u32    = unsigned int;
using f32x4  = __attribute__((ext_vector_type(4))) float;
using f32x16 = __attribute__((ext_vector_type(16))) float;
using bf16x8 = __attribute__((ext_vector_type(8))) __bf16;
using u16x4  = __attribute__((ext_vector_type(4))) u16;
using u32x2  = __attribute__((ext_vector_type(2))) u32;
using u32x4  = __attribute__((ext_vector_type(4))) u32;
using i32x4  = __attribute__((ext_vector_type(4))) int;

// B=2, S=2048, D=1024, H=16, DK=64, M=B*S=4096.
// Softmax in exp2 domain with FIXED m=0: p = 2^s (s = 0.125*log2e*qk, |s|<~12,
// no overflow; normalization cancels exactly). Fixed-m makes split-K partials
// combine by plain addition of (O, l).
//
// KP[bh][kt(32)][half(2)][chunk(8)][l31(32)] x16B  — in-loop K load = dense 1KB.
// VP[bh][kt(32)][chunk(8)][db(2)][l31(32)] x16B    — dense 2x512B per load.
// MP[b][kt(32)][q(2048)] u32x2                     — dense per-iter mask load.
//
// __launch_bounds__ 2nd arg caps UNIFIED VGPR+AGPR at 512/w. R9 measured
// 100 VGPR + ~64 acc = ~164 unified at w=2 (cap 256, 2 waves/SIMD resident).
// w=3 -> cap 170 >= 164: same allocation, 3 waves/SIMD. w=4 (cap 128) forced
// spills (R6/R8: 645MB scratch, 64V).

__device__ __forceinline__ u16 f2bf(float f) {
  union { __bf16 b; u16 u; } c; c.b = (__bf16)f; return c.u;
}

typedef __attribute__((address_space(1))) const void GVoid;
typedef __attribute__((address_space(3))) void LVoid;

__device__ __forceinline__ void gload_lds16(const void* g, void* l) {
  __builtin_amdgcn_global_load_lds((GVoid*)g, (LVoid*)l, 16, 0, 0);
}

// ---------------- fp32 -> bf16 conversion, all 7 arrays in one launch ----------------
__global__ void cvt_all(const float* __restrict__ q, const float* __restrict__ k,
                        const float* __restrict__ v, const float* __restrict__ wq,
                        const float* __restrict__ wk, const float* __restrict__ wv,
                        const float* __restrict__ wo,
                        u16* __restrict__ oq, u16* __restrict__ ok, u16* __restrict__ ov,
                        u16* __restrict__ owq, u16* __restrict__ owk,
                        u16* __restrict__ owv, u16* __restrict__ owo) {
  size_t u = (size_t)blockIdx.x * 256 + threadIdx.x;
  const float* s; u16* d; size_t off;
  int sel = (int)(u >> 20);
  if (sel < 3) {
    s = sel == 0 ? q : sel == 1 ? k : v;
    d = sel == 0 ? oq : sel == 1 ? ok : ov;
    off = u & 1048575;
  } else {
    int wsel = (int)(u >> 18) & 3;
    s = wsel == 0 ? wq : wsel == 1 ? wk : wsel == 2 ? wv : wo;
    d = wsel == 0 ? owq : wsel == 1 ? owk : wsel == 2 ? owv : owo;
    off = u & 262143;
  }
  f32x4 x = ((const f32x4*)s)[off];
  u16x4 r;
#pragma unroll
  for (int j = 0; j < 4; ++j) r[j] = f2bf(x[j]);
  ((u16x4*)d)[off] = r;
}

// ---------------- mask bit-pack + transpose: [B,S,S] i32 -> MP[b][kt][q] u32x2 ----------------
__global__ void pack_mask(const int* __restrict__ m, u32* __restrict__ mp) {
  int tid = blockIdx.x * 256 + threadIdx.x;  // 131072 = 2*32*2048
  int q = tid & 2047, kt = (tid >> 11) & 31, b = tid >> 16;
  const i32x4* src = (const i32x4*)(m + ((size_t)(b * 2048 + q)) * 2048 + kt * 64);
  u32 w0 = 0, w1 = 0;
#pragma unroll
  for (int j = 0; j < 8; ++j) {
    i32x4 a = src[j], c = src[j + 8];
#pragma unroll
    for (int e = 0; e < 4; ++e) {
      w0 |= (a[e] != 0 ? 1u : 0u) << (j * 4 + e);
      w1 |= (c[e] != 0 ? 1u : 0u) << (j * 4 + e);
    }
  }
  ((u32x2*)mp)[((size_t)(b * 32 + kt)) * 2048 + q] = u32x2{w0, w1};
}

// ---------------- GEMM: out[m,n] = sum_k X[m,k]*W[n,k] (x @ W.T) ----------------
// e: 0 = Q -> [B,H,S,DK] bf16 (pre-scaled); 3 = K -> KP packed; 1 = V -> VP packed;
// 2 = fp32 row-major [M,N] (final projection)
__global__ __launch_bounds__(256, 2) void gemm_bt(const u16* __restrict__ X,
                                                  const u16* __restrict__ W,
                                                  void* __restrict__ out, int epi) {
  __shared__ alignas(16) char lds[32768];
  const int t = threadIdx.x;
  const int lane = t & 63, wid = t >> 6;
  const int g = lane >> 4, r16 = lane & 15;
  const int wm = wid >> 1, wn = wid & 1;
  const int m0 = blockIdx.x * 128, n0 = blockIdx.y * 128;

  const u16* Xp = X;
  const u16* Wp = W;
  void* op = out;
  int e = epi;
  float qsc = 1.0f;
  if (epi < 0) {
    int z = blockIdx.z;
    Xp += (size_t)z * 4194304;
    Wp += (size_t)z * 1048576;
    op = (void*)((u16*)out + (size_t)z * 4194304);
    e = (z == 0) ? 0 : (z == 1) ? 3 : 1;
    if (z == 0) qsc = 0.18033688011f;  // 0.125 * log2(e) folded into Q
  }
  const char* Ab = (const char*)Xp;
  const char* Bb = (const char*)Wp;

  f32x4 acc[4][4] = {};

  for (int kk = 0; kk < 1024; kk += 64) {
#pragma unroll
    for (int i = 0; i < 4; ++i) {
      int ci = i * 256 + t;
      int row = ci >> 3;
      int cbs = ((ci & 7) << 4) ^ ((row & 7) << 4);
      gload_lds16(Ab + (size_t)(m0 + row) * 2048 + kk * 2 + cbs, lds + ci * 16);
      gload_lds16(Bb + (size_t)(n0 + row) * 2048 + kk * 2 + cbs, lds + 16384 + ci * 16);
    }
    __syncthreads();
#pragma unroll
    for (int kc = 0; kc < 2; ++kc) {
      bf16x8 af[4], bfr[4];
#pragma unroll
      for (int mf = 0; mf < 4; ++mf) {
        int row = wm * 64 + mf * 16 + r16;
        af[mf] = *(const bf16x8*)(lds + row * 128 + ((64 * kc + 16 * g) ^ ((row & 7) << 4)));
      }
#pragma unroll
      for (int nf = 0; nf < 4; ++nf) {
        int row = wn * 64 + nf * 16 + r16;
        bfr[nf] = *(const bf16x8*)(lds + 16384 + row * 128 + ((64 * kc + 16 * g) ^ ((row & 7) << 4)));
      }
#pragma unroll
      for (int mf = 0; mf < 4; ++mf)
#pragma unroll
        for (int nf = 0; nf < 4; ++nf)
          acc[mf][nf] = __builtin_amdgcn_mfma_f32_16x16x32_bf16(af[mf], bfr[nf], acc[mf][nf], 0, 0, 0);
    }
    __syncthreads();
  }

#pragma unroll
  for (int mf = 0; mf < 4; ++mf) {
#pragma unroll
    for (int nf = 0; nf < 4; ++nf) {
      int mb = m0 + wm * 64 + mf * 16 + 4 * g;
      int n = n0 + wn * 64 + nf * 16 + r16;
      if (e == 2) {
        float* O = (float*)op;
#pragma unroll
        for (int r = 0; r < 4; ++r) O[(size_t)(mb + r) * 1024 + n] = acc[mf][nf][r];
      } else if (e == 0) {  // Q: [B,H,S,DK]
        u16* O = (u16*)op;
        int bb = mb >> 11, h = n >> 6, dk = n & 63;
#pragma unroll
        for (int r = 0; r < 4; ++r) {
          int s = (mb + r) & 2047;
          O[((size_t)(bb * 16 + h) * 2048 + s) * 64 + dk] = f2bf(acc[mf][nf][r] * qsc);
        }
      } else if (e == 3) {  // K packed: KP[bh][kt][half][chunk][l31] x16B
        u16* O = (u16*)op;
        int h = n >> 6, dk = n & 63;
#pragma unroll
        for (int r = 0; r < 4; ++r) {
          int m = mb + r;
          int bb = m >> 11, s = m & 2047;
          size_t off16 = ((((size_t)(bb * 16 + h) * 32 + (s >> 6)) * 2 + ((s >> 5) & 1)) * 8 +
                          (dk >> 3)) * 32 + (s & 31);
          O[off16 * 8 + (dk & 7)] = f2bf(acc[mf][nf][r]);
        }
      } else {  // V packed: VP[bh][kt][chunk][db][l31] x16B; r -> consecutive j
        u16* O = (u16*)op;
        int bb = mb >> 11, s = mb & 2047, h = n >> 6, d = n & 63;
        size_t off16 = ((((size_t)(bb * 16 + h) * 32 + (s >> 6)) * 8 + ((s & 63) >> 3)) * 2 +
                        (d >> 5)) * 32 + (d & 31);
        u16x4 pv;
#pragma unroll
        for (int r = 0; r < 4; ++r) pv[r] = f2bf(acc[mf][nf][r]);
        *(u16x4*)(O + off16 * 8 + (s & 7)) = pv;
      }
    }
  }
}

// ---------------- flash attention: zero-LDS main loop, split-K x2 across waves ----------------
// 256-thread blocks: 4 waves = {qsub 0,1} x {k-half 0,1}. Each wave: 32 q-rows,
// 16 k-tiles. Fixed-m partials combine by LDS add. (Exact R9 body; only the
// launch bound changed 2 -> 3.)
struct KF { bf16x8 k0[4], k1[4]; };

__device__ __forceinline__ void loadK(KF& f, const char* p) {
#pragma unroll
  for (int c = 0; c < 4; ++c) {
    f.k0[c] = *(const bf16x8*)(p + c * 1024);
    f.k1[c] = *(const bf16x8*)(p + 4096 + c * 1024);
  }
}

__device__ __forceinline__ void attn_body(const bf16x8 (&qf)[4], KF& cur, KF& nxt,
                                          const char*& kp, const char*& vp0,
                                          const char*& vp1, const u32x2*& mptr,
                                          u32x2& mcur, int hi,
                                          f32x16& o0, f32x16& o1, float& l_run) {
  // V for CURRENT tile (consumed at PV ~400cy later: L2 latency hidden in-iter)
  bf16x8 v0[4], v1[4];
#pragma unroll
  for (int ks = 0; ks < 4; ++ks) {
    v0[ks] = *(const bf16x8*)(vp0 + ks * 2048);
    v1[ks] = *(const bf16x8*)(vp1 + ks * 2048);
  }
  // K + mask for NEXT tile
  loadK(nxt, kp);
  u32x2 mnext = *mptr;
  kp += 8192; vp0 += 8192; vp1 += 8192; mptr += 2048;
  __builtin_amdgcn_sched_barrier(0);  // pin load issue above compute

  // QK^T: S[k][q], C = 0
  f32x16 s0 = {}, s1 = {};
#pragma unroll
  for (int c = 0; c < 4; ++c) {
    s0 = __builtin_amdgcn_mfma_f32_32x32x16_bf16(cur.k0[c], qf[c], s0, 0, 0, 0);
    s1 = __builtin_amdgcn_mfma_f32_32x32x16_bf16(cur.k1[c], qf[c], s1, 0, 0, 0);
  }

  // p = 2^s, then zero masked via sign-extend + AND on float bits
  u32 wa = mcur.x >> (4 * hi), wb = mcur.y >> (4 * hi);
  float ps = 0.f;
#pragma unroll
  for (int r = 0; r < 16; ++r) {
    const int bit = (r & 3) + 8 * (r >> 2);
    float p0 = __builtin_amdgcn_exp2f(s0[r]);
    float p1 = __builtin_amdgcn_exp2f(s1[r]);
    int sm0 = ((int)(wa << (31 - bit))) >> 31;  // bit set -> -1 (keep), else 0
    int sm1 = ((int)(wb << (31 - bit))) >> 31;
    p0 = __uint_as_float(__float_as_uint(p0) & (u32)sm0);
    p1 = __uint_as_float(__float_as_uint(p1) & (u32)sm1);
    s0[r] = p0; s1[r] = p1;
    ps += p0 + p1;
  }
  l_run += ps;

  // P -> bf16 A-fragments (16 cvt_pk + 8 permlane32_swap)
  u32 w[16];
#pragma unroll
  for (int kb = 0; kb < 2; ++kb) {
#pragma unroll
    for (int ss = 0; ss < 2; ++ss) {
      const f32x16& sp = kb ? s1 : s0;
      u32 A0, B0, A1, B1;
      asm("v_cvt_pk_bf16_f32 %0, %1, %2" : "=v"(A0) : "v"(sp[8*ss+0]), "v"(sp[8*ss+1]));
      asm("v_cvt_pk_bf16_f32 %0, %1, %2" : "=v"(B0) : "v"(sp[8*ss+2]), "v"(sp[8*ss+3]));
      asm("v_cvt_pk_bf16_f32 %0, %1, %2" : "=v"(A1) : "v"(sp[8*ss+4]), "v"(sp[8*ss+5]));
      asm("v_cvt_pk_bf16_f32 %0, %1, %2" : "=v"(B1) : "v"(sp[8*ss+6]), "v"(sp[8*ss+7]));
      asm("v_permlane32_swap_b32 %0, %1" : "+v"(A0), "+v"(A1));
      asm("v_permlane32_swap_b32 %0, %1" : "+v"(B0), "+v"(B1));
      int f = 2 * kb + ss;
      w[4*f+0] = A0; w[4*f+1] = B0; w[4*f+2] = A1; w[4*f+3] = B1;
    }
  }

  // PV: O[q][d] += P[q,k] * V[k,d]
#pragma unroll
  for (int ks = 0; ks < 4; ++ks) {
    bf16x8 pa = __builtin_bit_cast(bf16x8, u32x4{w[4*ks], w[4*ks+1], w[4*ks+2], w[4*ks+3]});
    o0 = __builtin_amdgcn_mfma_f32_32x32x16_bf16(pa, v0[ks], o0, 0, 0, 0);
    o1 = __builtin_amdgcn_mfma_f32_32x32x16_bf16(pa, v1[ks], o1, 0, 0, 0);
  }
  mcur = mnext;
}

__global__ __launch_bounds__(256, 3) void attn_kern(const u16* __restrict__ Qh,
                                                    const u16* __restrict__ Kh,
                                                    const u16* __restrict__ Vt,
                                                    const u32* __restrict__ mp,
                                                    u16* __restrict__ ctx) {
  __shared__ float cmb[2][32][64];   // 16 KB: k-half-1 partial O per q-subtile
  __shared__ float cmbl[2][64];      // 512 B: k-half-1 partial l
  const int t = threadIdx.x;
  const int wid = t >> 6, lane = t & 63;
  const int qw = wid & 1, kh = wid >> 1;   // q-subtile, k-half
  const int hi = lane >> 5, l31 = lane & 31;

  // XCD-aware swizzle: 1024 blocks (32 q-tiles x 32 bh), 128-block chunk per XCD
  const int wg = (blockIdx.x & 7) * 128 + (blockIdx.x >> 3);
  const int qt = wg & 31, bh = wg >> 5;
  const int b = bh >> 4, h = bh & 15;

  const char* qbytes = (const char*)Qh;
  const int qbase = qt * 64 + qw * 32;
  const int qg = qbase + l31;

  // Q fragments (B operand): lane: q-col = l31, dk = 16c + 8hi + j  (one-time gather)
  bf16x8 qf[4];
#pragma unroll
  for (int c = 0; c < 4; ++c)
    qf[c] = *(const bf16x8*)(qbytes + ((size_t)bh * 2048 + qg) * 128 + 32 * c + 16 * hi);

  // per-lane packed pointers, offset to this wave's 16-tile k-half
  const char* kp  = (const char*)Kh + (size_t)bh * 262144 + (size_t)kh * 131072 + hi * 512 + l31 * 16;
  const char* vp0 = (const char*)Vt + (size_t)bh * 262144 + (size_t)kh * 131072 + hi * 1024 + l31 * 16;
  const char* vp1 = vp0 + 512;
  const u32x2* mptr = (const u32x2*)mp + (size_t)b * 65536 + (size_t)kh * 32768 + qg;

  f32x16 o0 = {}, o1 = {};
  float l_run = 0.f;

  KF A, B2;
  loadK(A, kp);
  kp += 8192;
  u32x2 mcur = *mptr;
  mptr += 2048;

#pragma unroll 1
  for (int it = 0; it < 8; ++it) {   // 16 k-tiles per wave (2 bodies/iter)
    attn_body(qf, A, B2, kp, vp0, vp1, mptr, mcur, hi, o0, o1, l_run);
    attn_body(qf, B2, A, kp, vp0, vp1, mptr, mcur, hi, o0, o1, l_run);
  }

  // per-wave row-sum (lane + partner ^32 cover all 64 k per tile)
  l_run += __shfl_xor(l_run, 32, 64);

  // split-K combine: waves kh=1 publish partials, waves kh=0 add + store
  if (kh) {
#pragma unroll
    for (int r = 0; r < 16; ++r) {
      cmb[qw][r][lane]      = o0[r];
      cmb[qw][16 + r][lane] = o1[r];
    }
    cmbl[qw][lane] = l_run;
  }
  __syncthreads();
  if (!kh) {
#pragma unroll
    for (int r = 0; r < 16; ++r) {
      o0[r] += cmb[qw][r][lane];
      o1[r] += cmb[qw][16 + r][lane];
    }
    l_run += cmbl[qw][lane];

    float rl = 1.f / l_run;
#pragma unroll
    for (int r = 0; r < 16; ++r) {
      float rv = __shfl(rl, (r & 3) + 8 * (r >> 2) + 4 * hi, 64);
      int q = qbase + (r & 3) + 8 * (r >> 2) + 4 * hi;
      size_t rowp = ((size_t)b * 2048 + q) * 1024 + h * 64 + l31;
      ctx[rowp]      = f2bf(o0[r] * rv);
      ctx[rowp + 32] = f2bf(o1[r] * rv);
    }
  }
}

// ---------------- launch ----------------
extern "C" void kernel_launch(void* const* d_in, const int* in_sizes, int n_in,
                              void* d_out, int out_size, void* d_ws, size_t ws_size,
                              hipStream_t stream) {
  const float* q  = (const float*)d_in[0];
  const float* k  = (const float*)d_in[1];
  const float* v  = (const float*)d_in[2];
  const int* mask = (const int*)d_in[3];
  const float* Wq = (const float*)d_in[4];
  const float* Wk = (const float*)d_in[5];
  const float* Wv = (const float*)d_in[6];
  const float* Wo = (const float*)d_in[7];

  u16* ws = (u16*)d_ws;
  const size_t NX = (size_t)4096 * 1024;
  const size_t NW = (size_t)1024 * 1024;
  u16* Xq  = ws;                    // dead after QKV GEMM -> reused for packed mask
  u16* Wqb = ws + 3 * NX;
  u16* Qh  = Wqb + 4 * NW;          // Qh | KP | VP consecutive
  u16* ctx = Qh + 3 * NX;
  u32* mpk = (u32*)Xq;              // 1 MB

  cvt_all<<<dim3(16384), 256, 0, stream>>>(q, k, v, Wq, Wk, Wv, Wo,
                                           Xq, Xq + NX, Xq + 2 * NX,
                                           Wqb, Wqb + NW, Wqb + 2 * NW, Wqb + 3 * NW);
  gemm_bt<<<dim3(32, 8, 3), 256, 0, stream>>>(Xq, Wqb, Qh, -1);
  pack_mask<<<dim3(512), 256, 0, stream>>>(mask, mpk);
  attn_kern<<<dim3(1024), 256, 0, stream>>>(Qh, Qh + NX, Qh + 2 * NX, mpk, ctx);
  gemm_bt<<<dim3(32, 8, 1), 256, 0, stream>>>(ctx, Wqb + 3 * NW, d_out, 2);
}

// Round 12
// 132.717 us; speedup vs baseline: 1.1993x; 1.1993x over previous
//
#include <hip/hip_runtime.h>

using u16    = unsigned short;
using u32    = unsigned int;
using f32x4  = __attribute__((ext_vector_type(4))) float;
using f32x16 = __attribute__((ext_vector_type(16))) float;
using bf16x8 = __attribute__((ext_vector_type(8))) __bf16;
using u16x4  = __attribute__((ext_vector_type(4))) u16;
using u16x8  = __attribute__((ext_vector_type(8))) u16;
using u32x2  = __attribute__((ext_vector_type(2))) u32;
using u32x4  = __attribute__((ext_vector_type(4))) u32;
using i32x4  = __attribute__((ext_vector_type(4))) int;

// B=2, S=2048, D=1024, H=16, DK=64, M=B*S=4096.
// Softmax in exp2 domain with FIXED m=0: p = 2^s (s = 0.125*log2e*qk, |s|<~12,
// no overflow; normalization cancels exactly). Fixed-m makes split-K partials
// combine by plain addition of (O, l).
//
// KP[bh][kt(32)][half(2)][chunk(8)][l31(32)] x16B  — in-loop K load = dense 1KB.
// VP[bh][kt(32)][chunk(8)][db(2)][l31(32)] x16B    — dense 2x512B per load.
// MP[b][kt(32)][q(2048)] u32x2                     — dense per-iter mask load.
//
// REGISTER LEDGER (R6/R8/R9/R11 evidence): attn body needs ~100 arch-VGPR +
// ~128 AGPR (s0,s1,o0,o1) = ~228 unified. Any __launch_bounds__ cap below that
// (w=3 -> 170, w=4 -> 128) forces spills (69-645 MB scratch). Keep (256,2).
// attn occupancy is register-capped at 2 waves/SIMD -> ~60us plateau.

__device__ __forceinline__ u16 f2bf(float f) {
  union { __bf16 b; u16 u; } c; c.b = (__bf16)f; return c.u;
}

typedef __attribute__((address_space(1))) const void GVoid;
typedef __attribute__((address_space(3))) void LVoid;

__device__ __forceinline__ void gload_lds16(const void* g, void* l) {
  __builtin_amdgcn_global_load_lds((GVoid*)g, (LVoid*)l, 16, 0, 0);
}

// ---------------- fp32 -> bf16 conversion: WEIGHTS ONLY (q/k/v now read fp32 in GEMM) ----------------
__global__ void cvt_w(const float* __restrict__ a, const float* __restrict__ b,
                      const float* __restrict__ c, const float* __restrict__ dd,
                      u16* __restrict__ oa, u16* __restrict__ ob,
                      u16* __restrict__ oc, u16* __restrict__ od) {
  int y = blockIdx.y;
  const float* s = (y == 0) ? a : (y == 1) ? b : (y == 2) ? c : dd;
  u16* d = (y == 0) ? oa : (y == 1) ? ob : (y == 2) ? oc : od;
  int i = blockIdx.x * 256 + threadIdx.x;
  f32x4 v = ((const f32x4*)s)[i];
  u16x4 r;
#pragma unroll
  for (int j = 0; j < 4; ++j) r[j] = f2bf(v[j]);
  ((u16x4*)d)[i] = r;
}

// ---------------- mask bit-pack + transpose: [B,S,S] i32 -> MP[b][kt][q] u32x2 ----------------
__global__ void pack_mask(const int* __restrict__ m, u32* __restrict__ mp) {
  int tid = blockIdx.x * 256 + threadIdx.x;  // 131072 = 2*32*2048
  int q = tid & 2047, kt = (tid >> 11) & 31, b = tid >> 16;
  const i32x4* src = (const i32x4*)(m + ((size_t)(b * 2048 + q)) * 2048 + kt * 64);
  u32 w0 = 0, w1 = 0;
#pragma unroll
  for (int j = 0; j < 8; ++j) {
    i32x4 a = src[j], c = src[j + 8];
#pragma unroll
    for (int e = 0; e < 4; ++e) {
      w0 |= (a[e] != 0 ? 1u : 0u) << (j * 4 + e);
      w1 |= (c[e] != 0 ? 1u : 0u) << (j * 4 + e);
    }
  }
  ((u32x2*)mp)[((size_t)(b * 32 + kt)) * 2048 + q] = u32x2{w0, w1};
}

// ---------------- QKV GEMM: A read DIRECTLY as fp32, reg-staged cvt into LDS ----------------
// out[m,n] = sum_k A[m,k] * W[n,k]; z = 0/1/2 -> Q/K/V epilogue layouts.
__global__ __launch_bounds__(256, 2) void gemm_qkv(const float* __restrict__ Aq,
                                                   const float* __restrict__ Ak,
                                                   const float* __restrict__ Av,
                                                   const u16* __restrict__ Wb,
                                                   u16* __restrict__ out) {
  __shared__ alignas(16) char lds[32768];
  const int t = threadIdx.x;
  const int lane = t & 63, wid = t >> 6;
  const int g = lane >> 4, r16 = lane & 15;
  const int wm = wid >> 1, wn = wid & 1;
  const int m0 = blockIdx.x * 128, n0 = blockIdx.y * 128;
  const int z = blockIdx.z;

  const float* Axf = (z == 0) ? Aq : (z == 1) ? Ak : Av;
  const char* Ab = (const char*)Axf;
  const char* Bb = (const char*)(Wb + (size_t)z * 1048576);
  u16* op = out + (size_t)z * 4194304;
  const float qsc = (z == 0) ? 0.18033688011f : 1.0f;  // 0.125*log2(e) folded into Q

  f32x4 acc[4][4] = {};

  for (int kk = 0; kk < 1024; kk += 64) {
    // B tile: async global->LDS (bf16 weights), swizzled source
#pragma unroll
    for (int i = 0; i < 4; ++i) {
      int ci = i * 256 + t;
      int row = ci >> 3;
      int cbs = ((ci & 7) << 4) ^ ((row & 7) << 4);
      gload_lds16(Bb + (size_t)(n0 + row) * 2048 + kk * 2 + cbs, lds + 16384 + ci * 16);
    }
    // A tile: fp32 reg-staged -> bf16 LDS (same swizzled element mapping: bf16
    // byte off cbs == fp32 byte off 2*cbs; 8 elems/thread -> one b128 write)
#pragma unroll
    for (int i = 0; i < 4; ++i) {
      int ci = i * 256 + t;
      int row = ci >> 3;
      int cbs = ((ci & 7) << 4) ^ ((row & 7) << 4);
      const char* src = Ab + (size_t)(m0 + row) * 4096 + kk * 4 + cbs * 2;
      f32x4 a0 = *(const f32x4*)(src);
      f32x4 a1 = *(const f32x4*)(src + 16);
      u16x8 pk;
#pragma unroll
      for (int j = 0; j < 4; ++j) { pk[j] = f2bf(a0[j]); pk[4 + j] = f2bf(a1[j]); }
      *(u16x8*)(lds + ci * 16) = pk;
    }
    __syncthreads();
#pragma unroll
    for (int kc = 0; kc < 2; ++kc) {
      bf16x8 af[4], bfr[4];
#pragma unroll
      for (int mf = 0; mf < 4; ++mf) {
        int row = wm * 64 + mf * 16 + r16;
        af[mf] = *(const bf16x8*)(lds + row * 128 + ((64 * kc + 16 * g) ^ ((row & 7) << 4)));
      }
#pragma unroll
      for (int nf = 0; nf < 4; ++nf) {
        int row = wn * 64 + nf * 16 + r16;
        bfr[nf] = *(const bf16x8*)(lds + 16384 + row * 128 + ((64 * kc + 16 * g) ^ ((row & 7) << 4)));
      }
#pragma unroll
      for (int mf = 0; mf < 4; ++mf)
#pragma unroll
        for (int nf = 0; nf < 4; ++nf)
          acc[mf][nf] = __builtin_amdgcn_mfma_f32_16x16x32_bf16(af[mf], bfr[nf], acc[mf][nf], 0, 0, 0);
    }
    __syncthreads();
  }

#pragma unroll
  for (int mf = 0; mf < 4; ++mf) {
#pragma unroll
    for (int nf = 0; nf < 4; ++nf) {
      int mb = m0 + wm * 64 + mf * 16 + 4 * g;
      int n = n0 + wn * 64 + nf * 16 + r16;
      if (z == 0) {  // Q: [B,H,S,DK] bf16, pre-scaled
        int bb = mb >> 11, h = n >> 6, dk = n & 63;
#pragma unroll
        for (int r = 0; r < 4; ++r) {
          int s = (mb + r) & 2047;
          op[((size_t)(bb * 16 + h) * 2048 + s) * 64 + dk] = f2bf(acc[mf][nf][r] * qsc);
        }
      } else if (z == 1) {  // K packed: KP[bh][kt][half][chunk][l31] x16B
        int h = n >> 6, dk = n & 63;
#pragma unroll
        for (int r = 0; r < 4; ++r) {
          int m = mb + r;
          int bb = m >> 11, s = m & 2047;
          size_t off16 = ((((size_t)(bb * 16 + h) * 32 + (s >> 6)) * 2 + ((s >> 5) & 1)) * 8 +
                          (dk >> 3)) * 32 + (s & 31);
          op[off16 * 8 + (dk & 7)] = f2bf(acc[mf][nf][r]);
        }
      } else {  // V packed: VP[bh][kt][chunk][db][l31] x16B; r -> consecutive j
        int bb = mb >> 11, s = mb & 2047, h = n >> 6, d = n & 63;
        size_t off16 = ((((size_t)(bb * 16 + h) * 32 + (s >> 6)) * 8 + ((s & 63) >> 3)) * 2 +
                        (d >> 5)) * 32 + (d & 31);
        u16x4 pv;
#pragma unroll
        for (int r = 0; r < 4; ++r) pv[r] = f2bf(acc[mf][nf][r]);
        *(u16x4*)(op + off16 * 8 + (s & 7)) = pv;
      }
    }
  }
}

// ---------------- out-projection GEMM: bf16 A (ctx), fp32 output ----------------
__global__ __launch_bounds__(256, 2) void gemm_out(const u16* __restrict__ X,
                                                   const u16* __restrict__ W,
                                                   float* __restrict__ out) {
  __shared__ alignas(16) char lds[32768];
  const int t = threadIdx.x;
  const int lane = t & 63, wid = t >> 6;
  const int g = lane >> 4, r16 = lane & 15;
  const int wm = wid >> 1, wn = wid & 1;
  const int m0 = blockIdx.x * 128, n0 = blockIdx.y * 128;
  const char* Ab = (const char*)X;
  const char* Bb = (const char*)W;

  f32x4 acc[4][4] = {};

  for (int kk = 0; kk < 1024; kk += 64) {
#pragma unroll
    for (int i = 0; i < 4; ++i) {
      int ci = i * 256 + t;
      int row = ci >> 3;
      int cbs = ((ci & 7) << 4) ^ ((row & 7) << 4);
      gload_lds16(Ab + (size_t)(m0 + row) * 2048 + kk * 2 + cbs, lds + ci * 16);
      gload_lds16(Bb + (size_t)(n0 + row) * 2048 + kk * 2 + cbs, lds + 16384 + ci * 16);
    }
    __syncthreads();
#pragma unroll
    for (int kc = 0; kc < 2; ++kc) {
      bf16x8 af[4], bfr[4];
#pragma unroll
      for (int mf = 0; mf < 4; ++mf) {
        int row = wm * 64 + mf * 16 + r16;
        af[mf] = *(const bf16x8*)(lds + row * 128 + ((64 * kc + 16 * g) ^ ((row & 7) << 4)));
      }
#pragma unroll
      for (int nf = 0; nf < 4; ++nf) {
        int row = wn * 64 + nf * 16 + r16;
        bfr[nf] = *(const bf16x8*)(lds + 16384 + row * 128 + ((64 * kc + 16 * g) ^ ((row & 7) << 4)));
      }
#pragma unroll
      for (int mf = 0; mf < 4; ++mf)
#pragma unroll
        for (int nf = 0; nf < 4; ++nf)
          acc[mf][nf] = __builtin_amdgcn_mfma_f32_16x16x32_bf16(af[mf], bfr[nf], acc[mf][nf], 0, 0, 0);
    }
    __syncthreads();
  }

#pragma unroll
  for (int mf = 0; mf < 4; ++mf)
#pragma unroll
    for (int nf = 0; nf < 4; ++nf) {
      int mb = m0 + wm * 64 + mf * 16 + 4 * g;
      int n = n0 + wn * 64 + nf * 16 + r16;
#pragma unroll
      for (int r = 0; r < 4; ++r) out[(size_t)(mb + r) * 1024 + n] = acc[mf][nf][r];
    }
}

// ---------------- flash attention: R9-exact (proven 60us / absmax 2e-3) ----------------
struct KF { bf16x8 k0[4], k1[4]; };

__device__ __forceinline__ void loadK(KF& f, const char* p) {
#pragma unroll
  for (int c = 0; c < 4; ++c) {
    f.k0[c] = *(const bf16x8*)(p + c * 1024);
    f.k1[c] = *(const bf16x8*)(p + 4096 + c * 1024);
  }
}

__device__ __forceinline__ void attn_body(const bf16x8 (&qf)[4], KF& cur, KF& nxt,
                                          const char*& kp, const char*& vp0,
                                          const char*& vp1, const u32x2*& mptr,
                                          u32x2& mcur, int hi,
                                          f32x16& o0, f32x16& o1, float& l_run) {
  // V for CURRENT tile (consumed at PV ~400cy later: L2 latency hidden in-iter)
  bf16x8 v0[4], v1[4];
#pragma unroll
  for (int ks = 0; ks < 4; ++ks) {
    v0[ks] = *(const bf16x8*)(vp0 + ks * 2048);
    v1[ks] = *(const bf16x8*)(vp1 + ks * 2048);
  }
  // K + mask for NEXT tile
  loadK(nxt, kp);
  u32x2 mnext = *mptr;
  kp += 8192; vp0 += 8192; vp1 += 8192; mptr += 2048;
  __builtin_amdgcn_sched_barrier(0);  // pin load issue above compute

  // QK^T: S[k][q], C = 0
  f32x16 s0 = {}, s1 = {};
#pragma unroll
  for (int c = 0; c < 4; ++c) {
    s0 = __builtin_amdgcn_mfma_f32_32x32x16_bf16(cur.k0[c], qf[c], s0, 0, 0, 0);
    s1 = __builtin_amdgcn_mfma_f32_32x32x16_bf16(cur.k1[c], qf[c], s1, 0, 0, 0);
  }

  // p = 2^s, then zero masked via sign-extend + AND on float bits
  u32 wa = mcur.x >> (4 * hi), wb = mcur.y >> (4 * hi);
  float ps = 0.f;
#pragma unroll
  for (int r = 0; r < 16; ++r) {
    const int bit = (r & 3) + 8 * (r >> 2);
    float p0 = __builtin_amdgcn_exp2f(s0[r]);
    float p1 = __builtin_amdgcn_exp2f(s1[r]);
    int sm0 = ((int)(wa << (31 - bit))) >> 31;  // bit set -> -1 (keep), else 0
    int sm1 = ((int)(wb << (31 - bit))) >> 31;
    p0 = __uint_as_float(__float_as_uint(p0) & (u32)sm0);
    p1 = __uint_as_float(__float_as_uint(p1) & (u32)sm1);
    s0[r] = p0; s1[r] = p1;
    ps += p0 + p1;
  }
  l_run += ps;

  // P -> bf16 A-fragments (16 cvt_pk + 8 permlane32_swap)
  u32 w[16];
#pragma unroll
  for (int kb = 0; kb < 2; ++kb) {
#pragma unroll
    for (int ss = 0; ss < 2; ++ss) {
      const f32x16& sp = kb ? s1 : s0;
      u32 A0, B0, A1, B1;
      asm("v_cvt_pk_bf16_f32 %0, %1, %2" : "=v"(A0) : "v"(sp[8*ss+0]), "v"(sp[8*ss+1]));
      asm("v_cvt_pk_bf16_f32 %0, %1, %2" : "=v"(B0) : "v"(sp[8*ss+2]), "v"(sp[8*ss+3]));
      asm("v_cvt_pk_bf16_f32 %0, %1, %2" : "=v"(A1) : "v"(sp[8*ss+4]), "v"(sp[8*ss+5]));
      asm("v_cvt_pk_bf16_f32 %0, %1, %2" : "=v"(B1) : "v"(sp[8*ss+6]), "v"(sp[8*ss+7]));
      asm("v_permlane32_swap_b32 %0, %1" : "+v"(A0), "+v"(A1));
      asm("v_permlane32_swap_b32 %0, %1" : "+v"(B0), "+v"(B1));
      int f = 2 * kb + ss;
      w[4*f+0] = A0; w[4*f+1] = B0; w[4*f+2] = A1; w[4*f+3] = B1;
    }
  }

  // PV: O[q][d] += P[q,k] * V[k,d]
#pragma unroll
  for (int ks = 0; ks < 4; ++ks) {
    bf16x8 pa = __builtin_bit_cast(bf16x8, u32x4{w[4*ks], w[4*ks+1], w[4*ks+2], w[4*ks+3]});
    o0 = __builtin_amdgcn_mfma_f32_32x32x16_bf16(pa, v0[ks], o0, 0, 0, 0);
    o1 = __builtin_amdgcn_mfma_f32_32x32x16_bf16(pa, v1[ks], o1, 0, 0, 0);
  }
  mcur = mnext;
}

__global__ __launch_bounds__(256, 2) void attn_kern(const u16* __restrict__ Qh,
                                                    const u16* __restrict__ Kh,
                                                    const u16* __restrict__ Vt,
                                                    const u32* __restrict__ mp,
                                                    u16* __restrict__ ctx) {
  __shared__ float cmb[2][32][64];   // 16 KB: k-half-1 partial O per q-subtile
  __shared__ float cmbl[2][64];      // 512 B: k-half-1 partial l
  const int t = threadIdx.x;
  const int wid = t >> 6, lane = t & 63;
  const int qw = wid & 1, kh = wid >> 1;   // q-subtile, k-half
  const int hi = lane >> 5, l31 = lane & 31;

  // XCD-aware swizzle: 1024 blocks (32 q-tiles x 32 bh), 128-block chunk per XCD
  const int wg = (blockIdx.x & 7) * 128 + (blockIdx.x >> 3);
  const int qt = wg & 31, bh = wg >> 5;
  const int b = bh >> 4, h = bh & 15;

  const char* qbytes = (const char*)Qh;
  const int qbase = qt * 64 + qw * 32;
  const int qg = qbase + l31;

  // Q fragments (B operand): lane: q-col = l31, dk = 16c + 8hi + j  (one-time gather)
  bf16x8 qf[4];
#pragma unroll
  for (int c = 0; c < 4; ++c)
    qf[c] = *(const bf16x8*)(qbytes + ((size_t)bh * 2048 + qg) * 128 + 32 * c + 16 * hi);

  // per-lane packed pointers, offset to this wave's 16-tile k-half
  const char* kp  = (const char*)Kh + (size_t)bh * 262144 + (size_t)kh * 131072 + hi * 512 + l31 * 16;
  const char* vp0 = (const char*)Vt + (size_t)bh * 262144 + (size_t)kh * 131072 + hi * 1024 + l31 * 16;
  const char* vp1 = vp0 + 512;
  const u32x2* mptr = (const u32x2*)mp + (size_t)b * 65536 + (size_t)kh * 32768 + qg;

  f32x16 o0 = {}, o1 = {};
  float l_run = 0.f;

  KF A, B2;
  loadK(A, kp);
  kp += 8192;
  u32x2 mcur = *mptr;
  mptr += 2048;

#pragma unroll 1
  for (int it = 0; it < 8; ++it) {   // 16 k-tiles per wave (2 bodies/iter)
    attn_body(qf, A, B2, kp, vp0, vp1, mptr, mcur, hi, o0, o1, l_run);
    attn_body(qf, B2, A, kp, vp0, vp1, mptr, mcur, hi, o0, o1, l_run);
  }

  // per-wave row-sum (lane + partner ^32 cover all 64 k per tile)
  l_run += __shfl_xor(l_run, 32, 64);

  // split-K combine: waves kh=1 publish partials, waves kh=0 add + store
  if (kh) {
#pragma unroll
    for (int r = 0; r < 16; ++r) {
      cmb[qw][r][lane]      = o0[r];
      cmb[qw][16 + r][lane] = o1[r];
    }
    cmbl[qw][lane] = l_run;
  }
  __syncthreads();
  if (!kh) {
#pragma unroll
    for (int r = 0; r < 16; ++r) {
      o0[r] += cmb[qw][r][lane];
      o1[r] += cmb[qw][16 + r][lane];
    }
    l_run += cmbl[qw][lane];

    float rl = 1.f / l_run;
#pragma unroll
    for (int r = 0; r < 16; ++r) {
      float rv = __shfl(rl, (r & 3) + 8 * (r >> 2) + 4 * hi, 64);
      int q = qbase + (r & 3) + 8 * (r >> 2) + 4 * hi;
      size_t rowp = ((size_t)b * 2048 + q) * 1024 + h * 64 + l31;
      ctx[rowp]      = f2bf(o0[r] * rv);
      ctx[rowp + 32] = f2bf(o1[r] * rv);
    }
  }
}

// ---------------- launch ----------------
extern "C" void kernel_launch(void* const* d_in, const int* in_sizes, int n_in,
                              void* d_out, int out_size, void* d_ws, size_t ws_size,
                              hipStream_t stream) {
  const float* q  = (const float*)d_in[0];
  const float* k  = (const float*)d_in[1];
  const float* v  = (const float*)d_in[2];
  const int* mask = (const int*)d_in[3];
  const float* Wq = (const float*)d_in[4];
  const float* Wk = (const float*)d_in[5];
  const float* Wv = (const float*)d_in[6];
  const float* Wo = (const float*)d_in[7];

  u16* ws = (u16*)d_ws;
  const size_t NX = (size_t)4096 * 1024;
  const size_t NW = (size_t)1024 * 1024;
  u16* Wqb = ws + 3 * NX;           // (first 3*NX region now only hosts mpk)
  u16* Qh  = Wqb + 4 * NW;          // Qh | KP | VP consecutive
  u16* ctx = Qh + 3 * NX;
  u32* mpk = (u32*)ws;              // 1 MB

  cvt_w<<<dim3(1024, 4), 256, 0, stream>>>(Wq, Wk, Wv, Wo,
                                           Wqb, Wqb + NW, Wqb + 2 * NW, Wqb + 3 * NW);
  pack_mask<<<dim3(512), 256, 0, stream>>>(mask, mpk);
  gemm_qkv<<<dim3(32, 8, 3), 256, 0, stream>>>(q, k, v, Wqb, Qh);
  attn_kern<<<dim3(1024), 256, 0, stream>>>(Qh, Qh + NX, Qh + 2 * NX, mpk, ctx);
  gemm_out<<<dim3(32, 8), 256, 0, stream>>>(ctx, Wqb + 3 * NW, (float*)d_out);
}

// Round 13
// 129.572 us; speedup vs baseline: 1.2284x; 1.0243x over previous
//
#include <hip/hip_runtime.h>

using u16    = unsigned short;
using u32    = unsigned int;
using f32x4  = __attribute__((ext_vector_type(4))) float;
using f32x16 = __attribute__((ext_vector_type(16))) float;
using bf16x8 = __attribute__((ext_vector_type(8))) __bf16;
using u16x4  = __attribute__((ext_vector_type(4))) u16;
using u16x8  = __attribute__((ext_vector_type(8))) u16;
using u32x2  = __attribute__((ext_vector_type(2))) u32;
using u32x4  = __attribute__((ext_vector_type(4))) u32;
using i32x4  = __attribute__((ext_vector_type(4))) int;

// B=2, S=2048, D=1024, H=16, DK=64, M=B*S=4096.
// Softmax in exp2 domain with FIXED m=0 (normalization cancels exactly).
// KP/VP/MP packed layouts as R5-R12. Register ledger: attn needs ~228 unified
// -> keep (256,2); caps below spill (R6/R8/R11 evidence).
// gemm_qkv: A read fp32 directly, reg-staged cvt -> LDS, SOFTWARE-PIPELINED
// (prefetch next A-tile into 2nd reg set; counted vmcnt(8) keeps it in flight).

__device__ __forceinline__ u16 f2bf(float f) {
  union { __bf16 b; u16 u; } c; c.b = (__bf16)f; return c.u;
}

typedef __attribute__((address_space(1))) const void GVoid;
typedef __attribute__((address_space(3))) void LVoid;

__device__ __forceinline__ void gload_lds16(const void* g, void* l) {
  __builtin_amdgcn_global_load_lds((GVoid*)g, (LVoid*)l, 16, 0, 0);
}

// ---------------- fp32 -> bf16 conversion: WEIGHTS ONLY ----------------
__global__ void cvt_w(const float* __restrict__ a, const float* __restrict__ b,
                      const float* __restrict__ c, const float* __restrict__ dd,
                      u16* __restrict__ oa, u16* __restrict__ ob,
                      u16* __restrict__ oc, u16* __restrict__ od) {
  int y = blockIdx.y;
  const float* s = (y == 0) ? a : (y == 1) ? b : (y == 2) ? c : dd;
  u16* d = (y == 0) ? oa : (y == 1) ? ob : (y == 2) ? oc : od;
  int i = blockIdx.x * 256 + threadIdx.x;
  f32x4 v = ((const f32x4*)s)[i];
  u16x4 r;
#pragma unroll
  for (int j = 0; j < 4; ++j) r[j] = f2bf(v[j]);
  ((u16x4*)d)[i] = r;
}

// ---------------- mask bit-pack + transpose: [B,S,S] i32 -> MP[b][kt][q] u32x2 ----------------
__global__ void pack_mask(const int* __restrict__ m, u32* __restrict__ mp) {
  int tid = blockIdx.x * 256 + threadIdx.x;  // 131072 = 2*32*2048
  int q = tid & 2047, kt = (tid >> 11) & 31, b = tid >> 16;
  const i32x4* src = (const i32x4*)(m + ((size_t)(b * 2048 + q)) * 2048 + kt * 64);
  u32 w0 = 0, w1 = 0;
#pragma unroll
  for (int j = 0; j < 8; ++j) {
    i32x4 a = src[j], c = src[j + 8];
#pragma unroll
    for (int e = 0; e < 4; ++e) {
      w0 |= (a[e] != 0 ? 1u : 0u) << (j * 4 + e);
      w1 |= (c[e] != 0 ? 1u : 0u) << (j * 4 + e);
    }
  }
  ((u32x2*)mp)[((size_t)(b * 32 + kt)) * 2048 + q] = u32x2{w0, w1};
}

// ---------------- QKV GEMM: fp32 A, reg-staged + pipelined; bf16 W via gload_lds ----------------
__global__ __launch_bounds__(256, 2) void gemm_qkv(const float* __restrict__ Aq,
                                                   const float* __restrict__ Ak,
                                                   const float* __restrict__ Av,
                                                   const u16* __restrict__ Wb,
                                                   u16* __restrict__ out) {
  __shared__ alignas(16) char lds[32768];
  const int t = threadIdx.x;
  const int lane = t & 63, wid = t >> 6;
  const int g = lane >> 4, r16 = lane & 15;
  const int wm = wid >> 1, wn = wid & 1;
  const int m0 = blockIdx.x * 128, n0 = blockIdx.y * 128;
  const int z = blockIdx.z;

  const float* Axf = (z == 0) ? Aq : (z == 1) ? Ak : Av;
  const char* Ab = (const char*)Axf;
  const char* Bb = (const char*)(Wb + (size_t)z * 1048576);
  u16* op = out + (size_t)z * 4194304;
  const float qsc = (z == 0) ? 0.18033688011f : 1.0f;  // 0.125*log2(e) into Q

  f32x4 acc[4][4] = {};

  auto loadA = [&](f32x4 (&d0)[4], f32x4 (&d1)[4], int kk) {
#pragma unroll
    for (int i = 0; i < 4; ++i) {
      int ci = i * 256 + t;
      int row = ci >> 3;
      int cbs = ((ci & 7) << 4) ^ ((row & 7) << 4);
      const char* src = Ab + (size_t)(m0 + row) * 4096 + kk * 4 + cbs * 2;
      d0[i] = *(const f32x4*)(src);
      d1[i] = *(const f32x4*)(src + 16);
    }
  };

  // body: stage tile kk from (c0,c1); prefetch kk+64 into (n0_,n1_) if pre
  auto body = [&](int kk, f32x4 (&c0)[4], f32x4 (&c1)[4],
                  f32x4 (&nn0)[4], f32x4 (&nn1)[4], bool pre) {
    // B tile: async global->LDS (4 loads)
#pragma unroll
    for (int i = 0; i < 4; ++i) {
      int ci = i * 256 + t;
      int row = ci >> 3;
      int cbs = ((ci & 7) << 4) ^ ((row & 7) << 4);
      gload_lds16(Bb + (size_t)(n0 + row) * 2048 + kk * 2 + cbs, lds + 16384 + ci * 16);
    }
    // A tile: cvt staged regs -> LDS (bit-identical mapping to gload_lds image)
#pragma unroll
    for (int i = 0; i < 4; ++i) {
      int ci = i * 256 + t;
      u16x8 pk;
#pragma unroll
      for (int j = 0; j < 4; ++j) { pk[j] = f2bf(c0[i][j]); pk[4 + j] = f2bf(c1[i][j]); }
      *(u16x8*)(lds + ci * 16) = pk;
    }
    if (pre) {
      loadA(nn0, nn1, kk + 64);  // 8 loads, stay in flight across the barrier
      asm volatile("s_waitcnt vmcnt(8) lgkmcnt(0)" ::: "memory");  // drain B + ds_write only
    } else {
      asm volatile("s_waitcnt vmcnt(0) lgkmcnt(0)" ::: "memory");
    }
    __builtin_amdgcn_s_barrier();
    asm volatile("" ::: "memory");
#pragma unroll
    for (int kc = 0; kc < 2; ++kc) {
      bf16x8 af[4], bfr[4];
#pragma unroll
      for (int mf = 0; mf < 4; ++mf) {
        int row = wm * 64 + mf * 16 + r16;
        af[mf] = *(const bf16x8*)(lds + row * 128 + ((64 * kc + 16 * g) ^ ((row & 7) << 4)));
      }
#pragma unroll
      for (int nf = 0; nf < 4; ++nf) {
        int row = wn * 64 + nf * 16 + r16;
        bfr[nf] = *(const bf16x8*)(lds + 16384 + row * 128 + ((64 * kc + 16 * g) ^ ((row & 7) << 4)));
      }
#pragma unroll
      for (int mf = 0; mf < 4; ++mf)
#pragma unroll
        for (int nf = 0; nf < 4; ++nf)
          acc[mf][nf] = __builtin_amdgcn_mfma_f32_16x16x32_bf16(af[mf], bfr[nf], acc[mf][nf], 0, 0, 0);
    }
    asm volatile("" ::: "memory");
    __builtin_amdgcn_s_barrier();  // LDS reads done before next iter's writes
    asm volatile("" ::: "memory");
  };

  f32x4 A0[4], A1[4], N0[4], N1[4];
  loadA(A0, A1, 0);
#pragma unroll 1
  for (int s = 0; s < 8; ++s) {
    body(s * 128,      A0, A1, N0, N1, true);
    body(s * 128 + 64, N0, N1, A0, A1, s < 7);
  }

#pragma unroll
  for (int mf = 0; mf < 4; ++mf) {
#pragma unroll
    for (int nf = 0; nf < 4; ++nf) {
      int mb = m0 + wm * 64 + mf * 16 + 4 * g;
      int n = n0 + wn * 64 + nf * 16 + r16;
      if (z == 0) {  // Q: [B,H,S,DK] bf16, pre-scaled
        int bb = mb >> 11, h = n >> 6, dk = n & 63;
#pragma unroll
        for (int r = 0; r < 4; ++r) {
          int s2 = (mb + r) & 2047;
          op[((size_t)(bb * 16 + h) * 2048 + s2) * 64 + dk] = f2bf(acc[mf][nf][r] * qsc);
        }
      } else if (z == 1) {  // K packed: KP[bh][kt][half][chunk][l31] x16B
        int h = n >> 6, dk = n & 63;
#pragma unroll
        for (int r = 0; r < 4; ++r) {
          int m = mb + r;
          int bb = m >> 11, s2 = m & 2047;
          size_t off16 = ((((size_t)(bb * 16 + h) * 32 + (s2 >> 6)) * 2 + ((s2 >> 5) & 1)) * 8 +
                          (dk >> 3)) * 32 + (s2 & 31);
          op[off16 * 8 + (dk & 7)] = f2bf(acc[mf][nf][r]);
        }
      } else {  // V packed: VP[bh][kt][chunk][db][l31] x16B
        int bb = mb >> 11, s2 = mb & 2047, h = n >> 6, d = n & 63;
        size_t off16 = ((((size_t)(bb * 16 + h) * 32 + (s2 >> 6)) * 8 + ((s2 & 63) >> 3)) * 2 +
                        (d >> 5)) * 32 + (d & 31);
        u16x4 pv;
#pragma unroll
        for (int r = 0; r < 4; ++r) pv[r] = f2bf(acc[mf][nf][r]);
        *(u16x4*)(op + off16 * 8 + (s2 & 7)) = pv;
      }
    }
  }
}

// ---------------- out-projection GEMM: bf16 A (ctx), fp32 output ----------------
__global__ __launch_bounds__(256, 2) void gemm_out(const u16* __restrict__ X,
                                                   const u16* __restrict__ W,
                                                   float* __restrict__ out) {
  __shared__ alignas(16) char lds[32768];
  const int t = threadIdx.x;
  const int lane = t & 63, wid = t >> 6;
  const int g = lane >> 4, r16 = lane & 15;
  const int wm = wid >> 1, wn = wid & 1;
  const int m0 = blockIdx.x * 128, n0 = blockIdx.y * 128;
  const char* Ab = (const char*)X;
  const char* Bb = (const char*)W;

  f32x4 acc[4][4] = {};

  for (int kk = 0; kk < 1024; kk += 64) {
#pragma unroll
    for (int i = 0; i < 4; ++i) {
      int ci = i * 256 + t;
      int row = ci >> 3;
      int cbs = ((ci & 7) << 4) ^ ((row & 7) << 4);
      gload_lds16(Ab + (size_t)(m0 + row) * 2048 + kk * 2 + cbs, lds + ci * 16);
      gload_lds16(Bb + (size_t)(n0 + row) * 2048 + kk * 2 + cbs, lds + 16384 + ci * 16);
    }
    __syncthreads();
#pragma unroll
    for (int kc = 0; kc < 2; ++kc) {
      bf16x8 af[4], bfr[4];
#pragma unroll
      for (int mf = 0; mf < 4; ++mf) {
        int row = wm * 64 + mf * 16 + r16;
        af[mf] = *(const bf16x8*)(lds + row * 128 + ((64 * kc + 16 * g) ^ ((row & 7) << 4)));
      }
#pragma unroll
      for (int nf = 0; nf < 4; ++nf) {
        int row = wn * 64 + nf * 16 + r16;
        bfr[nf] = *(const bf16x8*)(lds + 16384 + row * 128 + ((64 * kc + 16 * g) ^ ((row & 7) << 4)));
      }
#pragma unroll
      for (int mf = 0; mf < 4; ++mf)
#pragma unroll
        for (int nf = 0; nf < 4; ++nf)
          acc[mf][nf] = __builtin_amdgcn_mfma_f32_16x16x32_bf16(af[mf], bfr[nf], acc[mf][nf], 0, 0, 0);
    }
    __syncthreads();
  }

#pragma unroll
  for (int mf = 0; mf < 4; ++mf)
#pragma unroll
    for (int nf = 0; nf < 4; ++nf) {
      int mb = m0 + wm * 64 + mf * 16 + 4 * g;
      int n = n0 + wn * 64 + nf * 16 + r16;
#pragma unroll
      for (int r = 0; r < 4; ++r) out[(size_t)(mb + r) * 1024 + n] = acc[mf][nf][r];
    }
}

// ---------------- flash attention: R9-exact (proven 60us / absmax 2e-3) ----------------
struct KF { bf16x8 k0[4], k1[4]; };

__device__ __forceinline__ void loadK(KF& f, const char* p) {
#pragma unroll
  for (int c = 0; c < 4; ++c) {
    f.k0[c] = *(const bf16x8*)(p + c * 1024);
    f.k1[c] = *(const bf16x8*)(p + 4096 + c * 1024);
  }
}

__device__ __forceinline__ void attn_body(const bf16x8 (&qf)[4], KF& cur, KF& nxt,
                                          const char*& kp, const char*& vp0,
                                          const char*& vp1, const u32x2*& mptr,
                                          u32x2& mcur, int hi,
                                          f32x16& o0, f32x16& o1, float& l_run) {
  bf16x8 v0[4], v1[4];
#pragma unroll
  for (int ks = 0; ks < 4; ++ks) {
    v0[ks] = *(const bf16x8*)(vp0 + ks * 2048);
    v1[ks] = *(const bf16x8*)(vp1 + ks * 2048);
  }
  loadK(nxt, kp);
  u32x2 mnext = *mptr;
  kp += 8192; vp0 += 8192; vp1 += 8192; mptr += 2048;
  __builtin_amdgcn_sched_barrier(0);

  f32x16 s0 = {}, s1 = {};
#pragma unroll
  for (int c = 0; c < 4; ++c) {
    s0 = __builtin_amdgcn_mfma_f32_32x32x16_bf16(cur.k0[c], qf[c], s0, 0, 0, 0);
    s1 = __builtin_amdgcn_mfma_f32_32x32x16_bf16(cur.k1[c], qf[c], s1, 0, 0, 0);
  }

  u32 wa = mcur.x >> (4 * hi), wb = mcur.y >> (4 * hi);
  float ps = 0.f;
#pragma unroll
  for (int r = 0; r < 16; ++r) {
    const int bit = (r & 3) + 8 * (r >> 2);
    float p0 = __builtin_amdgcn_exp2f(s0[r]);
    float p1 = __builtin_amdgcn_exp2f(s1[r]);
    int sm0 = ((int)(wa << (31 - bit))) >> 31;
    int sm1 = ((int)(wb << (31 - bit))) >> 31;
    p0 = __uint_as_float(__float_as_uint(p0) & (u32)sm0);
    p1 = __uint_as_float(__float_as_uint(p1) & (u32)sm1);
    s0[r] = p0; s1[r] = p1;
    ps += p0 + p1;
  }
  l_run += ps;

  u32 w[16];
#pragma unroll
  for (int kb = 0; kb < 2; ++kb) {
#pragma unroll
    for (int ss = 0; ss < 2; ++ss) {
      const f32x16& sp = kb ? s1 : s0;
      u32 A0, B0, A1, B1;
      asm("v_cvt_pk_bf16_f32 %0, %1, %2" : "=v"(A0) : "v"(sp[8*ss+0]), "v"(sp[8*ss+1]));
      asm("v_cvt_pk_bf16_f32 %0, %1, %2" : "=v"(B0) : "v"(sp[8*ss+2]), "v"(sp[8*ss+3]));
      asm("v_cvt_pk_bf16_f32 %0, %1, %2" : "=v"(A1) : "v"(sp[8*ss+4]), "v"(sp[8*ss+5]));
      asm("v_cvt_pk_bf16_f32 %0, %1, %2" : "=v"(B1) : "v"(sp[8*ss+6]), "v"(sp[8*ss+7]));
      asm("v_permlane32_swap_b32 %0, %1" : "+v"(A0), "+v"(A1));
      asm("v_permlane32_swap_b32 %0, %1" : "+v"(B0), "+v"(B1));
      int f = 2 * kb + ss;
      w[4*f+0] = A0; w[4*f+1] = B0; w[4*f+2] = A1; w[4*f+3] = B1;
    }
  }

#pragma unroll
  for (int ks = 0; ks < 4; ++ks) {
    bf16x8 pa = __builtin_bit_cast(bf16x8, u32x4{w[4*ks], w[4*ks+1], w[4*ks+2], w[4*ks+3]});
    o0 = __builtin_amdgcn_mfma_f32_32x32x16_bf16(pa, v0[ks], o0, 0, 0, 0);
    o1 = __builtin_amdgcn_mfma_f32_32x32x16_bf16(pa, v1[ks], o1, 0, 0, 0);
  }
  mcur = mnext;
}

__global__ __launch_bounds__(256, 2) void attn_kern(const u16* __restrict__ Qh,
                                                    const u16* __restrict__ Kh,
                                                    const u16* __restrict__ Vt,
                                                    const u32* __restrict__ mp,
                                                    u16* __restrict__ ctx) {
  __shared__ float cmb[2][32][64];
  __shared__ float cmbl[2][64];
  const int t = threadIdx.x;
  const int wid = t >> 6, lane = t & 63;
  const int qw = wid & 1, kh = wid >> 1;
  const int hi = lane >> 5, l31 = lane & 31;

  const int wg = (blockIdx.x & 7) * 128 + (blockIdx.x >> 3);
  const int qt = wg & 31, bh = wg >> 5;
  const int b = bh >> 4, h = bh & 15;

  const char* qbytes = (const char*)Qh;
  const int qbase = qt * 64 + qw * 32;
  const int qg = qbase + l31;

  bf16x8 qf[4];
#pragma unroll
  for (int c = 0; c < 4; ++c)
    qf[c] = *(const bf16x8*)(qbytes + ((size_t)bh * 2048 + qg) * 128 + 32 * c + 16 * hi);

  const char* kp  = (const char*)Kh + (size_t)bh * 262144 + (size_t)kh * 131072 + hi * 512 + l31 * 16;
  const char* vp0 = (const char*)Vt + (size_t)bh * 262144 + (size_t)kh * 131072 + hi * 1024 + l31 * 16;
  const char* vp1 = vp0 + 512;
  const u32x2* mptr = (const u32x2*)mp + (size_t)b * 65536 + (size_t)kh * 32768 + qg;

  f32x16 o0 = {}, o1 = {};
  float l_run = 0.f;

  KF A, B2;
  loadK(A, kp);
  kp += 8192;
  u32x2 mcur = *mptr;
  mptr += 2048;

#pragma unroll 1
  for (int it = 0; it < 8; ++it) {
    attn_body(qf, A, B2, kp, vp0, vp1, mptr, mcur, hi, o0, o1, l_run);
    attn_body(qf, B2, A, kp, vp0, vp1, mptr, mcur, hi, o0, o1, l_run);
  }

  l_run += __shfl_xor(l_run, 32, 64);

  if (kh) {
#pragma unroll
    for (int r = 0; r < 16; ++r) {
      cmb[qw][r][lane]      = o0[r];
      cmb[qw][16 + r][lane] = o1[r];
    }
    cmbl[qw][lane] = l_run;
  }
  __syncthreads();
  if (!kh) {
#pragma unroll
    for (int r = 0; r < 16; ++r) {
      o0[r] += cmb[qw][r][lane];
      o1[r] += cmb[qw][16 + r][lane];
    }
    l_run += cmbl[qw][lane];

    float rl = 1.f / l_run;
#pragma unroll
    for (int r = 0; r < 16; ++r) {
      float rv = __shfl(rl, (r & 3) + 8 * (r >> 2) + 4 * hi, 64);
      int q = qbase + (r & 3) + 8 * (r >> 2) + 4 * hi;
      size_t rowp = ((size_t)b * 2048 + q) * 1024 + h * 64 + l31;
      ctx[rowp]      = f2bf(o0[r] * rv);
      ctx[rowp + 32] = f2bf(o1[r] * rv);
    }
  }
}

// ---------------- launch ----------------
extern "C" void kernel_launch(void* const* d_in, const int* in_sizes, int n_in,
                              void* d_out, int out_size, void* d_ws, size_t ws_size,
                              hipStream_t stream) {
  const float* q  = (const float*)d_in[0];
  const float* k  = (const float*)d_in[1];
  const float* v  = (const float*)d_in[2];
  const int* mask = (const int*)d_in[3];
  const float* Wq = (const float*)d_in[4];
  const float* Wk = (const float*)d_in[5];
  const float* Wv = (const float*)d_in[6];
  const float* Wo = (const float*)d_in[7];

  u16* ws = (u16*)d_ws;
  const size_t NX = (size_t)4096 * 1024;
  const size_t NW = (size_t)1024 * 1024;
  u16* Wqb = ws + 3 * NX;
  u16* Qh  = Wqb + 4 * NW;          // Qh | KP | VP consecutive
  u16* ctx = Qh + 3 * NX;
  u32* mpk = (u32*)ws;              // 1 MB

  cvt_w<<<dim3(1024, 4), 256, 0, stream>>>(Wq, Wk, Wv, Wo,
                                           Wqb, Wqb + NW, Wqb + 2 * NW, Wqb + 3 * NW);
  pack_mask<<<dim3(512), 256, 0, stream>>>(mask, mpk);
  gemm_qkv<<<dim3(32, 8, 3), 256, 0, stream>>>(q, k, v, Wqb, Qh);
  attn_kern<<<dim3(1024), 256, 0, stream>>>(Qh, Qh + NX, Qh + 2 * NX, mpk, ctx);
  gemm_out<<<dim3(32, 8), 256, 0, stream>>>(ctx, Wqb + 3 * NW, (float*)d_out);
}

// Round 14
// 125.885 us; speedup vs baseline: 1.2644x; 1.0293x over previous
//
#include <hip/hip_runtime.h>

using u16    = unsigned short;
using u32    = unsigned int;
using f32x4  = __attribute__((ext_vector_type(4))) float;
using f32x16 = __attribute__((ext_vector_type(16))) float;
using bf16x8 = __attribute__((ext_vector_type(8))) __bf16;
using u16x4  = __attribute__((ext_vector_type(4))) u16;
using u16x8  = __attribute__((ext_vector_type(8))) u16;
using u32x2  = __attribute__((ext_vector_type(2))) u32;
using u32x4  = __attribute__((ext_vector_type(4))) u32;
using i32x4  = __attribute__((ext_vector_type(4))) int;

// B=2, S=2048, D=1024, H=16, DK=64, M=B*S=4096.
// Softmax in exp2 domain with FIXED m=0 (normalization cancels exactly).
// KP/VP/MP packed layouts as R5-R13. Register ledger: attn needs ~228 unified
// -> keep (256,2); caps below spill (R6/R8/R11 evidence).
// gemm_qkv: A staged as RAW FP32 via global_load_lds (async, 32KB tile),
// bf16 cvt at fragment-read time. A-swizzle: 16B chunk ^ (row&15), source-side.

__device__ __forceinline__ u16 f2bf(float f) {
  union { __bf16 b; u16 u; } c; c.b = (__bf16)f; return c.u;
}

typedef __attribute__((address_space(1))) const void GVoid;
typedef __attribute__((address_space(3))) void LVoid;

__device__ __forceinline__ void gload_lds16(const void* g, void* l) {
  __builtin_amdgcn_global_load_lds((GVoid*)g, (LVoid*)l, 16, 0, 0);
}

// ---------------- fp32 -> bf16 conversion: WEIGHTS ONLY ----------------
__global__ void cvt_w(const float* __restrict__ a, const float* __restrict__ b,
                      const float* __restrict__ c, const float* __restrict__ dd,
                      u16* __restrict__ oa, u16* __restrict__ ob,
                      u16* __restrict__ oc, u16* __restrict__ od) {
  int y = blockIdx.y;
  const float* s = (y == 0) ? a : (y == 1) ? b : (y == 2) ? c : dd;
  u16* d = (y == 0) ? oa : (y == 1) ? ob : (y == 2) ? oc : od;
  int i = blockIdx.x * 256 + threadIdx.x;
  f32x4 v = ((const f32x4*)s)[i];
  u16x4 r;
#pragma unroll
  for (int j = 0; j < 4; ++j) r[j] = f2bf(v[j]);
  ((u16x4*)d)[i] = r;
}

// ---------------- mask bit-pack + transpose: [B,S,S] i32 -> MP[b][kt][q] u32x2 ----------------
__global__ void pack_mask(const int* __restrict__ m, u32* __restrict__ mp) {
  int tid = blockIdx.x * 256 + threadIdx.x;  // 131072 = 2*32*2048
  int q = tid & 2047, kt = (tid >> 11) & 31, b = tid >> 16;
  const i32x4* src = (const i32x4*)(m + ((size_t)(b * 2048 + q)) * 2048 + kt * 64);
  u32 w0 = 0, w1 = 0;
#pragma unroll
  for (int j = 0; j < 8; ++j) {
    i32x4 a = src[j], c = src[j + 8];
#pragma unroll
    for (int e = 0; e < 4; ++e) {
      w0 |= (a[e] != 0 ? 1u : 0u) << (j * 4 + e);
      w1 |= (c[e] != 0 ? 1u : 0u) << (j * 4 + e);
    }
  }
  ((u32x2*)mp)[((size_t)(b * 32 + kt)) * 2048 + q] = u32x2{w0, w1};
}

// ---------------- QKV GEMM: A fp32 via global_load_lds, cvt at fragment read ----------------
// out[m,n] = sum_k A[m,k] * W[n,k]; z = 0/1/2 -> Q/K/V epilogue layouts.
// LDS: A fp32 [128][64] = 32KB (16B chunks swizzled: phys = logical ^ (row&15)),
//      B bf16 [128][64] = 16KB at +32768 (R13 layout).
__global__ __launch_bounds__(256, 2) void gemm_qkv(const float* __restrict__ Aq,
                                                   const float* __restrict__ Ak,
                                                   const float* __restrict__ Av,
                                                   const u16* __restrict__ Wb,
                                                   u16* __restrict__ out) {
  __shared__ alignas(16) char lds[49152];
  const int t = threadIdx.x;
  const int lane = t & 63, wid = t >> 6;
  const int g = lane >> 4, r16 = lane & 15;
  const int wm = wid >> 1, wn = wid & 1;
  const int m0 = blockIdx.x * 128, n0 = blockIdx.y * 128;
  const int z = blockIdx.z;

  const float* Axf = (z == 0) ? Aq : (z == 1) ? Ak : Av;
  const char* Ab = (const char*)Axf;
  const char* Bb = (const char*)(Wb + (size_t)z * 1048576);
  u16* op = out + (size_t)z * 4194304;
  const float qsc = (z == 0) ? 0.18033688011f : 1.0f;  // 0.125*log2(e) into Q

  f32x4 acc[4][4] = {};

  for (int kk = 0; kk < 1024; kk += 64) {
    // A tile: fp32 [128 rows][64 k] -> 32KB, 8 async issues; source pre-swizzled
    // so that logical 16B chunk L of row r lives at physical chunk L ^ (r&15).
#pragma unroll
    for (int i = 0; i < 8; ++i) {
      int ci = i * 256 + t;          // 16B slot
      int row = ci >> 4;
      int pc = ci & 15;
      int lc = pc ^ (row & 15);
      gload_lds16(Ab + (size_t)(m0 + row) * 4096 + kk * 4 + lc * 16, lds + ci * 16);
    }
    // B tile: bf16 weights, 4 async issues (R13 swizzle)
#pragma unroll
    for (int i = 0; i < 4; ++i) {
      int ci = i * 256 + t;
      int row = ci >> 3;
      int cbs = ((ci & 7) << 4) ^ ((row & 7) << 4);
      gload_lds16(Bb + (size_t)(n0 + row) * 2048 + kk * 2 + cbs, lds + 32768 + ci * 16);
    }
    __syncthreads();
#pragma unroll
    for (int kc = 0; kc < 2; ++kc) {
      bf16x8 af[4], bfr[4];
#pragma unroll
      for (int mf = 0; mf < 4; ++mf) {
        int row = wm * 64 + mf * 16 + r16;
        const char* arow = lds + row * 256;
        int x = row & 15;
        int lc0 = 8 * kc + 2 * g;    // logical 16B chunk of k = 32kc+8g
        f32x4 alo = *(const f32x4*)(arow + ((lc0 ^ x) * 16));
        f32x4 ahi = *(const f32x4*)(arow + (((lc0 + 1) ^ x) * 16));
        u16x8 pk;
#pragma unroll
        for (int j = 0; j < 4; ++j) { pk[j] = f2bf(alo[j]); pk[4 + j] = f2bf(ahi[j]); }
        af[mf] = __builtin_bit_cast(bf16x8, pk);
      }
#pragma unroll
      for (int nf = 0; nf < 4; ++nf) {
        int row = wn * 64 + nf * 16 + r16;
        bfr[nf] = *(const bf16x8*)(lds + 32768 + row * 128 +
                                   ((64 * kc + 16 * g) ^ ((row & 7) << 4)));
      }
#pragma unroll
      for (int mf = 0; mf < 4; ++mf)
#pragma unroll
        for (int nf = 0; nf < 4; ++nf)
          acc[mf][nf] = __builtin_amdgcn_mfma_f32_16x16x32_bf16(af[mf], bfr[nf], acc[mf][nf], 0, 0, 0);
    }
    __syncthreads();
  }

#pragma unroll
  for (int mf = 0; mf < 4; ++mf) {
#pragma unroll
    for (int nf = 0; nf < 4; ++nf) {
      int mb = m0 + wm * 64 + mf * 16 + 4 * g;
      int n = n0 + wn * 64 + nf * 16 + r16;
      if (z == 0) {  // Q: [B,H,S,DK] bf16, pre-scaled
        int bb = mb >> 11, h = n >> 6, dk = n & 63;
#pragma unroll
        for (int r = 0; r < 4; ++r) {
          int s2 = (mb + r) & 2047;
          op[((size_t)(bb * 16 + h) * 2048 + s2) * 64 + dk] = f2bf(acc[mf][nf][r] * qsc);
        }
      } else if (z == 1) {  // K packed: KP[bh][kt][half][chunk][l31] x16B
        int h = n >> 6, dk = n & 63;
#pragma unroll
        for (int r = 0; r < 4; ++r) {
          int m = mb + r;
          int bb = m >> 11, s2 = m & 2047;
          size_t off16 = ((((size_t)(bb * 16 + h) * 32 + (s2 >> 6)) * 2 + ((s2 >> 5) & 1)) * 8 +
                          (dk >> 3)) * 32 + (s2 & 31);
          op[off16 * 8 + (dk & 7)] = f2bf(acc[mf][nf][r]);
        }
      } else {  // V packed: VP[bh][kt][chunk][db][l31] x16B
        int bb = mb >> 11, s2 = mb & 2047, h = n >> 6, d = n & 63;
        size_t off16 = ((((size_t)(bb * 16 + h) * 32 + (s2 >> 6)) * 8 + ((s2 & 63) >> 3)) * 2 +
                        (d >> 5)) * 32 + (d & 31);
        u16x4 pv;
#pragma unroll
        for (int r = 0; r < 4; ++r) pv[r] = f2bf(acc[mf][nf][r]);
        *(u16x4*)(op + off16 * 8 + (s2 & 7)) = pv;
      }
    }
  }
}

// ---------------- out-projection GEMM: bf16 A (ctx), fp32 output ----------------
__global__ __launch_bounds__(256, 2) void gemm_out(const u16* __restrict__ X,
                                                   const u16* __restrict__ W,
                                                   float* __restrict__ out) {
  __shared__ alignas(16) char lds[32768];
  const int t = threadIdx.x;
  const int lane = t & 63, wid = t >> 6;
  const int g = lane >> 4, r16 = lane & 15;
  const int wm = wid >> 1, wn = wid & 1;
  const int m0 = blockIdx.x * 128, n0 = blockIdx.y * 128;
  const char* Ab = (const char*)X;
  const char* Bb = (const char*)W;

  f32x4 acc[4][4] = {};

  for (int kk = 0; kk < 1024; kk += 64) {
#pragma unroll
    for (int i = 0; i < 4; ++i) {
      int ci = i * 256 + t;
      int row = ci >> 3;
      int cbs = ((ci & 7) << 4) ^ ((row & 7) << 4);
      gload_lds16(Ab + (size_t)(m0 + row) * 2048 + kk * 2 + cbs, lds + ci * 16);
      gload_lds16(Bb + (size_t)(n0 + row) * 2048 + kk * 2 + cbs, lds + 16384 + ci * 16);
    }
    __syncthreads();
#pragma unroll
    for (int kc = 0; kc < 2; ++kc) {
      bf16x8 af[4], bfr[4];
#pragma unroll
      for (int mf = 0; mf < 4; ++mf) {
        int row = wm * 64 + mf * 16 + r16;
        af[mf] = *(const bf16x8*)(lds + row * 128 + ((64 * kc + 16 * g) ^ ((row & 7) << 4)));
      }
#pragma unroll
      for (int nf = 0; nf < 4; ++nf) {
        int row = wn * 64 + nf * 16 + r16;
        bfr[nf] = *(const bf16x8*)(lds + 16384 + row * 128 + ((64 * kc + 16 * g) ^ ((row & 7) << 4)));
      }
#pragma unroll
      for (int mf = 0; mf < 4; ++mf)
#pragma unroll
        for (int nf = 0; nf < 4; ++nf)
          acc[mf][nf] = __builtin_amdgcn_mfma_f32_16x16x32_bf16(af[mf], bfr[nf], acc[mf][nf], 0, 0, 0);
    }
    __syncthreads();
  }

#pragma unroll
  for (int mf = 0; mf < 4; ++mf)
#pragma unroll
    for (int nf = 0; nf < 4; ++nf) {
      int mb = m0 + wm * 64 + mf * 16 + 4 * g;
      int n = n0 + wn * 64 + nf * 16 + r16;
#pragma unroll
      for (int r = 0; r < 4; ++r) out[(size_t)(mb + r) * 1024 + n] = acc[mf][nf][r];
    }
}

// ---------------- flash attention: R9-exact (proven 60us / absmax 2e-3) ----------------
struct KF { bf16x8 k0[4], k1[4]; };

__device__ __forceinline__ void loadK(KF& f, const char* p) {
#pragma unroll
  for (int c = 0; c < 4; ++c) {
    f.k0[c] = *(const bf16x8*)(p + c * 1024);
    f.k1[c] = *(const bf16x8*)(p + 4096 + c * 1024);
  }
}

__device__ __forceinline__ void attn_body(const bf16x8 (&qf)[4], KF& cur, KF& nxt,
                                          const char*& kp, const char*& vp0,
                                          const char*& vp1, const u32x2*& mptr,
                                          u32x2& mcur, int hi,
                                          f32x16& o0, f32x16& o1, float& l_run) {
  bf16x8 v0[4], v1[4];
#pragma unroll
  for (int ks = 0; ks < 4; ++ks) {
    v0[ks] = *(const bf16x8*)(vp0 + ks * 2048);
    v1[ks] = *(const bf16x8*)(vp1 + ks * 2048);
  }
  loadK(nxt, kp);
  u32x2 mnext = *mptr;
  kp += 8192; vp0 += 8192; vp1 += 8192; mptr += 2048;
  __builtin_amdgcn_sched_barrier(0);

  f32x16 s0 = {}, s1 = {};
#pragma unroll
  for (int c = 0; c < 4; ++c) {
    s0 = __builtin_amdgcn_mfma_f32_32x32x16_bf16(cur.k0[c], qf[c], s0, 0, 0, 0);
    s1 = __builtin_amdgcn_mfma_f32_32x32x16_bf16(cur.k1[c], qf[c], s1, 0, 0, 0);
  }

  u32 wa = mcur.x >> (4 * hi), wb = mcur.y >> (4 * hi);
  float ps = 0.f;
#pragma unroll
  for (int r = 0; r < 16; ++r) {
    const int bit = (r & 3) + 8 * (r >> 2);
    float p0 = __builtin_amdgcn_exp2f(s0[r]);
    float p1 = __builtin_amdgcn_exp2f(s1[r]);
    int sm0 = ((int)(wa << (31 - bit))) >> 31;
    int sm1 = ((int)(wb << (31 - bit))) >> 31;
    p0 = __uint_as_float(__float_as_uint(p0) & (u32)sm0);
    p1 = __uint_as_float(__float_as_uint(p1) & (u32)sm1);
    s0[r] = p0; s1[r] = p1;
    ps += p0 + p1;
  }
  l_run += ps;

  u32 w[16];
#pragma unroll
  for (int kb = 0; kb < 2; ++kb) {
#pragma unroll
    for (int ss = 0; ss < 2; ++ss) {
      const f32x16& sp = kb ? s1 : s0;
      u32 A0, B0, A1, B1;
      asm("v_cvt_pk_bf16_f32 %0, %1, %2" : "=v"(A0) : "v"(sp[8*ss+0]), "v"(sp[8*ss+1]));
      asm("v_cvt_pk_bf16_f32 %0, %1, %2" : "=v"(B0) : "v"(sp[8*ss+2]), "v"(sp[8*ss+3]));
      asm("v_cvt_pk_bf16_f32 %0, %1, %2" : "=v"(A1) : "v"(sp[8*ss+4]), "v"(sp[8*ss+5]));
      asm("v_cvt_pk_bf16_f32 %0, %1, %2" : "=v"(B1) : "v"(sp[8*ss+6]), "v"(sp[8*ss+7]));
      asm("v_permlane32_swap_b32 %0, %1" : "+v"(A0), "+v"(A1));
      asm("v_permlane32_swap_b32 %0, %1" : "+v"(B0), "+v"(B1));
      int f = 2 * kb + ss;
      w[4*f+0] = A0; w[4*f+1] = B0; w[4*f+2] = A1; w[4*f+3] = B1;
    }
  }

#pragma unroll
  for (int ks = 0; ks < 4; ++ks) {
    bf16x8 pa = __builtin_bit_cast(bf16x8, u32x4{w[4*ks], w[4*ks+1], w[4*ks+2], w[4*ks+3]});
    o0 = __builtin_amdgcn_mfma_f32_32x32x16_bf16(pa, v0[ks], o0, 0, 0, 0);
    o1 = __builtin_amdgcn_mfma_f32_32x32x16_bf16(pa, v1[ks], o1, 0, 0, 0);
  }
  mcur = mnext;
}

__global__ __launch_bounds__(256, 2) void attn_kern(const u16* __restrict__ Qh,
                                                    const u16* __restrict__ Kh,
                                                    const u16* __restrict__ Vt,
                                                    const u32* __restrict__ mp,
                                                    u16* __restrict__ ctx) {
  __shared__ float cmb[2][32][64];
  __shared__ float cmbl[2][64];
  const int t = threadIdx.x;
  const int wid = t >> 6, lane = t & 63;
  const int qw = wid & 1, kh = wid >> 1;
  const int hi = lane >> 5, l31 = lane & 31;

  const int wg = (blockIdx.x & 7) * 128 + (blockIdx.x >> 3);
  const int qt = wg & 31, bh = wg >> 5;
  const int b = bh >> 4, h = bh & 15;

  const char* qbytes = (const char*)Qh;
  const int qbase = qt * 64 + qw * 32;
  const int qg = qbase + l31;

  bf16x8 qf[4];
#pragma unroll
  for (int c = 0; c < 4; ++c)
    qf[c] = *(const bf16x8*)(qbytes + ((size_t)bh * 2048 + qg) * 128 + 32 * c + 16 * hi);

  const char* kp  = (const char*)Kh + (size_t)bh * 262144 + (size_t)kh * 131072 + hi * 512 + l31 * 16;
  const char* vp0 = (const char*)Vt + (size_t)bh * 262144 + (size_t)kh * 131072 + hi * 1024 + l31 * 16;
  const char* vp1 = vp0 + 512;
  const u32x2* mptr = (const u32x2*)mp + (size_t)b * 65536 + (size_t)kh * 32768 + qg;

  f32x16 o0 = {}, o1 = {};
  float l_run = 0.f;

  KF A, B2;
  loadK(A, kp);
  kp += 8192;
  u32x2 mcur = *mptr;
  mptr += 2048;

#pragma unroll 1
  for (int it = 0; it < 8; ++it) {
    attn_body(qf, A, B2, kp, vp0, vp1, mptr, mcur, hi, o0, o1, l_run);
    attn_body(qf, B2, A, kp, vp0, vp1, mptr, mcur, hi, o0, o1, l_run);
  }

  l_run += __shfl_xor(l_run, 32, 64);

  if (kh) {
#pragma unroll
    for (int r = 0; r < 16; ++r) {
      cmb[qw][r][lane]      = o0[r];
      cmb[qw][16 + r][lane] = o1[r];
    }
    cmbl[qw][lane] = l_run;
  }
  __syncthreads();
  if (!kh) {
#pragma unroll
    for (int r = 0; r < 16; ++r) {
      o0[r] += cmb[qw][r][lane];
      o1[r] += cmb[qw][16 + r][lane];
    }
    l_run += cmbl[qw][lane];

    float rl = 1.f / l_run;
#pragma unroll
    for (int r = 0; r < 16; ++r) {
      float rv = __shfl(rl, (r & 3) + 8 * (r >> 2) + 4 * hi, 64);
      int q = qbase + (r & 3) + 8 * (r >> 2) + 4 * hi;
      size_t rowp = ((size_t)b * 2048 + q) * 1024 + h * 64 + l31;
      ctx[rowp]      = f2bf(o0[r] * rv);
      ctx[rowp + 32] = f2bf(o1[r] * rv);
    }
  }
}

// ---------------- launch ----------------
extern "C" void kernel_launch(void* const* d_in, const int* in_sizes, int n_in,
                              void* d_out, int out_size, void* d_ws, size_t ws_size,
                              hipStream_t stream) {
  const float* q  = (const float*)d_in[0];
  const float* k  = (const float*)d_in[1];
  const float* v  = (const float*)d_in[2];
  const int* mask = (const int*)d_in[3];
  const float* Wq = (const float*)d_in[4];
  const float* Wk = (const float*)d_in[5];
  const float* Wv = (const float*)d_in[6];
  const float* Wo = (const float*)d_in[7];

  u16* ws = (u16*)d_ws;
  const size_t NX = (size_t)4096 * 1024;
  const size_t NW = (size_t)1024 * 1024;
  u16* Wqb = ws + 3 * NX;
  u16* Qh  = Wqb + 4 * NW;          // Qh | KP | VP consecutive
  u16* ctx = Qh + 3 * NX;
  u32* mpk = (u32*)ws;              // 1 MB

  cvt_w<<<dim3(1024, 4), 256, 0, stream>>>(Wq, Wk, Wv, Wo,
                                           Wqb, Wqb + NW, Wqb + 2 * NW, Wqb + 3 * NW);
  pack_mask<<<dim3(512), 256, 0, stream>>>(mask, mpk);
  gemm_qkv<<<dim3(32, 8, 3), 256, 0, stream>>>(q, k, v, Wqb, Qh);
  attn_kern<<<dim3(1024), 256, 0, stream>>>(Qh, Qh + NX, Qh + 2 * NX, mpk, ctx);
  gemm_out<<<dim3(32, 8), 256, 0, stream>>>(ctx, Wqb + 3 * NW, (float*)d_out);
}